// Round 15
// baseline (235.432 us; speedup 1.0000x reference)
//
#include <hip/hip_runtime.h>
#include <hip/hip_bf16.h>
#include <math.h>

#define E_    8
#define HID_  1024
#define FFN_  2048
#define M_    2048     // B*S
#define NP_   (M_*2)   // total (token, expert) pairs

typedef __attribute__((ext_vector_type(8))) short bf16x8;
typedef __attribute__((ext_vector_type(4))) float f32x4;
typedef __attribute__((ext_vector_type(4))) int   i32x4;

typedef const __attribute__((address_space(1))) void GVOID;
typedef __attribute__((address_space(3))) void LVOID;

__device__ __forceinline__ short f2bf(float f) {
    union { __hip_bfloat16 b; short s; } u;
    u.b = __float2bfloat16(f);
    return u.s;
}

// pack 8 consecutive-k fp32 (two f32x4) into one bf16x8 fragment (RNE)
__device__ __forceinline__ bf16x8 pk8(f32x4 lo, f32x4 hi) {
    unsigned u0, u1, u2, u3;
    asm("v_cvt_pk_bf16_f32 %0, %1, %2" : "=v"(u0) : "v"(lo.x), "v"(lo.y));
    asm("v_cvt_pk_bf16_f32 %0, %1, %2" : "=v"(u1) : "v"(lo.z), "v"(lo.w));
    asm("v_cvt_pk_bf16_f32 %0, %1, %2" : "=v"(u2) : "v"(hi.x), "v"(hi.y));
    asm("v_cvt_pk_bf16_f32 %0, %1, %2" : "=v"(u3) : "v"(hi.z), "v"(hi.w));
    union { i32x4 i; bf16x8 b; } r;
    r.i = (i32x4){(int)u0, (int)u1, (int)u2, (int)u3};
    return r.b;
}

// ---------------------------------------------------------------------------
// Router (+ fused x->bf16 conversion): one wave per token.  [proven]
// ---------------------------------------------------------------------------
__global__ __launch_bounds__(64) void router_kernel(
    const float* __restrict__ x, const float* __restrict__ rw,
    const float* __restrict__ rb, int* __restrict__ ids,
    float* __restrict__ wts, int* __restrict__ cnt,
    float* __restrict__ topk_out, __hip_bfloat16* __restrict__ xb)
{
    const int m    = blockIdx.x;
    const int lane = threadIdx.x;
    const float4* xm4 = (const float4*)(x + (size_t)m * HID_);

    float4 xv[4];
#pragma unroll
    for (int j = 0; j < 4; ++j) xv[j] = xm4[j*64 + lane];

    short4* xbr = (short4*)(xb + (size_t)m * HID_);
#pragma unroll
    for (int j = 0; j < 4; ++j) {
        short4 o;
        o.x = f2bf(xv[j].x); o.y = f2bf(xv[j].y);
        o.z = f2bf(xv[j].z); o.w = f2bf(xv[j].w);
        xbr[j*64 + lane] = o;
    }

    float lg[E_];
#pragma unroll
    for (int e = 0; e < E_; ++e) {
        const float4* we4 = (const float4*)(rw + e * HID_);
        float s = 0.f;
#pragma unroll
        for (int j = 0; j < 4; ++j) {
            float4 w = we4[j*64 + lane];
            s = fmaf(xv[j].x, w.x, s);
            s = fmaf(xv[j].y, w.y, s);
            s = fmaf(xv[j].z, w.z, s);
            s = fmaf(xv[j].w, w.w, s);
        }
        lg[e] = s;
    }
#pragma unroll
    for (int off = 32; off; off >>= 1)
#pragma unroll
        for (int e = 0; e < E_; ++e) lg[e] += __shfl_xor(lg[e], off);

    if (lane == 0) {
        float l2[E_], p[E_];
        float mx = -1e30f;
#pragma unroll
        for (int e = 0; e < E_; ++e) { l2[e] = lg[e] + rb[e]; mx = fmaxf(mx, l2[e]); }
        float sum = 0.f;
#pragma unroll
        for (int e = 0; e < E_; ++e) { p[e] = expf(l2[e] - mx); sum += p[e]; }
        float inv = 1.f / sum;
#pragma unroll
        for (int e = 0; e < E_; ++e) p[e] *= inv;

        int   i1 = -1, i2 = -1;
        float v1 = -1e30f, v2 = -1e30f;
#pragma unroll
        for (int e = 0; e < E_; ++e) {
            float pe = p[e];
            if (pe > v1)      { v2 = v1; i2 = i1; v1 = pe; i1 = e; }
            else if (pe > v2) { v2 = pe; i2 = e; }
        }
        ids[2*m]   = i1;  ids[2*m+1]   = i2;
        wts[2*m]   = v1;  wts[2*m+1]   = v2;
        topk_out[2*m]   = v1;
        topk_out[2*m+1] = v2;
        atomicAdd(&cnt[i1], 1);
        atomicAdd(&cnt[i2], 1);
    }
}

__global__ void offsets_kernel(const int* __restrict__ cnt,
                               int* __restrict__ off, int* __restrict__ fill)
{
    if (threadIdx.x == 0 && blockIdx.x == 0) {
        int acc = 0;
        for (int e = 0; e < E_; ++e) { off[e] = acc; fill[e] = acc; acc += cnt[e]; }
    }
}

__global__ __launch_bounds__(256) void scatter_kernel(
    const int* __restrict__ ids, const float* __restrict__ wts,
    int* __restrict__ fill, int* __restrict__ gtok, float* __restrict__ gwt,
    int* __restrict__ pos)
{
    int m = blockIdx.x * 256 + threadIdx.x;
    if (m >= M_) return;
#pragma unroll
    for (int s = 0; s < 2; ++s) {
        int e = ids[2*m + s];
        int p = atomicAdd(&fill[e], 1);
        gtok[p] = m;
        gwt[p]  = wts[2*m + s];
        pos[2*m + s] = p;
    }
}

// ===========================================================================
// TIER-2 GEMMs, NO weight pre-conversion. B (fp32) is staged into TWO 8KB
// LDS arrays with 64B rows (Blo = k[0,16), Bhi = k[16,32) of each row) so the
// bank index keeps the row bit: bank = (r&1)*16 + chunk*4 + j  ->  <=2-way
// (round-14's single 128B-row tile was 8-way conflicted: 4.7M conflicts).
// Chunk swizzle c = p ^ ((r>>1)&3) applied on stage SOURCE, inverted on read.
// Double-buffered 48KB (3 blocks/CU), 2-phase: STAGE(t+1)->COMPUTE(t)->bar.
// ===========================================================================

// GEMM1: 128 gathered tokens x 64 h-cols. K = HID = 1024, NT = 32 steps.
__global__ __launch_bounds__(256, 3) void gemm1_kernel(
    const __hip_bfloat16* __restrict__ xb, const float* __restrict__ w1,
    const float* __restrict__ w1b, const int* __restrict__ gtok,
    const int* __restrict__ cnt, const int* __restrict__ off,
    __hip_bfloat16* __restrict__ h)
{
    const int e  = blockIdx.z;
    const int ce = cnt[e];
    const int t0 = blockIdx.y * 128;
    if (t0 >= ce) return;
    const int n0   = blockIdx.x * 64;
    const int base = off[e];
    const float* w1e = w1 + (size_t)e * (2*FFN_) * HID_;

    __shared__ __align__(16) __hip_bfloat16 As[2][128*32];   // 8KB each
    __shared__ __align__(16) float Blo[2][128*16];           // 8KB each
    __shared__ __align__(16) float Bhi[2][128*16];           // 8KB each

    const int tid  = threadIdx.x;
    const int lane = tid & 63;
    const int wid  = tid >> 6;
    const int wm   = wid >> 1;
    const int wn   = wid & 1;
    const int cf   = lane >> 4;

    // A stage sources (2 x 16B per thread), bf16 4-chunk swizzle
    const __hip_bfloat16* asrc[2];
#pragma unroll
    for (int q = 0; q < 2; ++q) {
        int slot = q*256 + tid;
        int r = slot >> 2, p = slot & 3;
        int c = p ^ ((r >> 1) & 3);
        int rr  = min(t0 + r, ce - 1);
        asrc[q] = xb + (size_t)gtok[base + rr] * HID_ + c*8;
    }
    // B stage sources: q=0,1 -> Blo (k-half 0), q=2,3 -> Bhi (k-half 16)
    const float* bsrc[4];
#pragma unroll
    for (int q = 0; q < 4; ++q) {
        int slot = (q & 1)*256 + tid;        // 0..511 within the half
        int r = slot >> 2, p = slot & 3;
        int c = p ^ ((r >> 1) & 3);
        int gk = (q >> 1) ? (16 + c*4) : (c*4);
        int q2 = r >> 5, s = r & 31;
        int grow = (q2 & 1) ? (FFN_ + n0 + (q2>>1)*32 + s)
                            : (       n0 + (q2>>1)*32 + s);
        bsrc[q] = w1e + (size_t)grow * HID_ + gk;
    }

    auto STAGE = [&](int b, int k0) {
#pragma unroll
        for (int q = 0; q < 2; ++q)
            __builtin_amdgcn_global_load_lds((GVOID*)(asrc[q] + k0),
                (LVOID*)(&As[b][(q*256 + wid*64)*8]), 16, 0, 0);
#pragma unroll
        for (int q = 0; q < 2; ++q)
            __builtin_amdgcn_global_load_lds((GVOID*)(bsrc[q] + k0),
                (LVOID*)(&Blo[b][((q&1)*256 + wid*64)*4]), 16, 0, 0);
#pragma unroll
        for (int q = 2; q < 4; ++q)
            __builtin_amdgcn_global_load_lds((GVOID*)(bsrc[q] + k0),
                (LVOID*)(&Bhi[b][((q&1)*256 + wid*64)*4]), 16, 0, 0);
    };

    f32x4 acc[4][4];
#pragma unroll
    for (int m = 0; m < 4; ++m)
#pragma unroll
        for (int n = 0; n < 4; ++n) acc[m][n] = (f32x4){0.f,0.f,0.f,0.f};

    auto COMPUTE = [&](int cb) {
        bf16x8 af[4], bfr[4];
#pragma unroll
        for (int m = 0; m < 4; ++m) {
            int r = wm*64 + m*16 + (lane & 15);
            int sw = cf ^ ((r >> 1) & 3);
            af[m] = *(bf16x8*)&As[cb][r*32 + sw*8];
        }
#pragma unroll
        for (int n = 0; n < 4; ++n) {
            int r = wn*64 + n*16 + (lane & 15);
            int sw3 = (r >> 1) & 3;
            int g0 = (2*cf) & 3;                 // global chunk within half
            int p0 = g0 ^ sw3, p1 = (g0+1) ^ sw3;
            const float* arr = (cf < 2) ? &Blo[cb][0] : &Bhi[cb][0];
            f32x4 lo4 = *(f32x4*)&arr[r*16 + p0*4];
            f32x4 hi4 = *(f32x4*)&arr[r*16 + p1*4];
            bfr[n] = pk8(lo4, hi4);
        }
        __builtin_amdgcn_s_setprio(1);
#pragma unroll
        for (int m = 0; m < 4; ++m)
#pragma unroll
            for (int n = 0; n < 4; ++n)
                acc[m][n] = __builtin_amdgcn_mfma_f32_16x16x32_bf16(
                    af[m], bfr[n], acc[m][n], 0, 0, 0);
        __builtin_amdgcn_s_setprio(0);
    };

    const int NT = HID_/32;   // 32
    STAGE(0, 0);
    __syncthreads();
    for (int t = 0; t < NT; ++t) {
        int cur = t & 1, nxt = cur ^ 1;
        if (t + 1 < NT) STAGE(nxt, (t+1)*32);
        COMPUTE(cur);
        __syncthreads();
    }

    // Epilogue: fused SiLU(gate)*up -> h (bf16)
    const float* w1be = w1b + e*2*FFN_;
#pragma unroll
    for (int n = 0; n < 2; ++n) {
        int col = n0 + wn*32 + n*16 + (lane & 15);
        float bg = w1be[col];
        float bu = w1be[FFN_ + col];
#pragma unroll
        for (int m = 0; m < 4; ++m) {
            int rb2 = t0 + wm*64 + m*16 + (lane >> 4)*4;
#pragma unroll
            for (int i = 0; i < 4; ++i) {
                int t = rb2 + i;
                if (t < ce) {
                    float g = acc[m][n][i]   + bg;
                    float u = acc[m][n+2][i] + bu;
                    float hv = (g / (1.f + __expf(-g))) * u;
                    h[(size_t)(base + t)*FFN_ + col] = __float2bfloat16(hv);
                }
            }
        }
    }
}

// GEMM2: 128 pairs x 128 hid cols, split-K=2 (z = e + 8*ks). B = w2 fp32
// staged into Blo/Bhi + cvt at read. Plain stores into dpair[ks].
__global__ __launch_bounds__(256, 3) void gemm2_kernel(
    const __hip_bfloat16* __restrict__ h, const float* __restrict__ w2,
    const float* __restrict__ w2b, const float* __restrict__ gwt,
    const int* __restrict__ cnt, const int* __restrict__ off,
    float* __restrict__ dpair)
{
    const int e  = blockIdx.z & 7;
    const int ks = blockIdx.z >> 3;
    const int ce = cnt[e];
    const int t0 = blockIdx.y * 128;
    if (t0 >= ce) return;
    const int n0    = blockIdx.x * 128;
    const int base  = off[e];
    const int kbase = ks * (FFN_/2);
    const float* w2e = w2 + (size_t)e * HID_ * FFN_;

    __shared__ __align__(16) __hip_bfloat16 As[2][128*32];
    __shared__ __align__(16) float Blo[2][128*16];
    __shared__ __align__(16) float Bhi[2][128*16];

    const int tid  = threadIdx.x;
    const int lane = tid & 63;
    const int wid  = tid >> 6;
    const int wm   = wid >> 1;
    const int wn   = wid & 1;
    const int cf   = lane >> 4;

    const __hip_bfloat16* asrc[2];
#pragma unroll
    for (int q = 0; q < 2; ++q) {
        int slot = q*256 + tid;
        int r = slot >> 2, p = slot & 3;
        int c = p ^ ((r >> 1) & 3);
        int rr = min(t0 + r, ce - 1);
        asrc[q] = h + (size_t)(base + rr) * FFN_ + kbase + c*8;
    }
    const float* bsrc[4];
#pragma unroll
    for (int q = 0; q < 4; ++q) {
        int slot = (q & 1)*256 + tid;
        int r = slot >> 2, p = slot & 3;
        int c = p ^ ((r >> 1) & 3);
        int gk = (q >> 1) ? (16 + c*4) : (c*4);
        bsrc[q] = w2e + (size_t)(n0 + r) * FFN_ + kbase + gk;
    }

    auto STAGE = [&](int b, int k0) {
#pragma unroll
        for (int q = 0; q < 2; ++q)
            __builtin_amdgcn_global_load_lds((GVOID*)(asrc[q] + k0),
                (LVOID*)(&As[b][(q*256 + wid*64)*8]), 16, 0, 0);
#pragma unroll
        for (int q = 0; q < 2; ++q)
            __builtin_amdgcn_global_load_lds((GVOID*)(bsrc[q] + k0),
                (LVOID*)(&Blo[b][((q&1)*256 + wid*64)*4]), 16, 0, 0);
#pragma unroll
        for (int q = 2; q < 4; ++q)
            __builtin_amdgcn_global_load_lds((GVOID*)(bsrc[q] + k0),
                (LVOID*)(&Bhi[b][((q&1)*256 + wid*64)*4]), 16, 0, 0);
    };

    f32x4 acc[4][4];
#pragma unroll
    for (int m = 0; m < 4; ++m)
#pragma unroll
        for (int n = 0; n < 4; ++n) acc[m][n] = (f32x4){0.f,0.f,0.f,0.f};

    auto COMPUTE = [&](int cb) {
        bf16x8 af[4], bfr[4];
#pragma unroll
        for (int m = 0; m < 4; ++m) {
            int r = wm*64 + m*16 + (lane & 15);
            int sw = cf ^ ((r >> 1) & 3);
            af[m] = *(bf16x8*)&As[cb][r*32 + sw*8];
        }
#pragma unroll
        for (int n = 0; n < 4; ++n) {
            int r = wn*64 + n*16 + (lane & 15);
            int sw3 = (r >> 1) & 3;
            int g0 = (2*cf) & 3;
            int p0 = g0 ^ sw3, p1 = (g0+1) ^ sw3;
            const float* arr = (cf < 2) ? &Blo[cb][0] : &Bhi[cb][0];
            f32x4 lo4 = *(f32x4*)&arr[r*16 + p0*4];
            f32x4 hi4 = *(f32x4*)&arr[r*16 + p1*4];
            bfr[n] = pk8(lo4, hi4);
        }
        __builtin_amdgcn_s_setprio(1);
#pragma unroll
        for (int m = 0; m < 4; ++m)
#pragma unroll
            for (int n = 0; n < 4; ++n)
                acc[m][n] = __builtin_amdgcn_mfma_f32_16x16x32_bf16(
                    af[m], bfr[n], acc[m][n], 0, 0, 0);
        __builtin_amdgcn_s_setprio(0);
    };

    const int NT = (FFN_/2)/32;   // 32
    STAGE(0, 0);
    __syncthreads();
    for (int t = 0; t < NT; ++t) {
        int cur = t & 1, nxt = cur ^ 1;
        if (t + 1 < NT) STAGE(nxt, (t+1)*32);
        COMPUTE(cur);
        __syncthreads();
    }

    const float* w2be = w2b + e*HID_;
    float* dpk = dpair + (size_t)ks * NP_ * HID_;
#pragma unroll
    for (int n = 0; n < 4; ++n) {
        int col = n0 + wn*64 + n*16 + (lane & 15);
        float bias = (ks == 0) ? w2be[col] : 0.f;
#pragma unroll
        for (int m = 0; m < 4; ++m) {
            int rb2 = t0 + wm*64 + m*16 + (lane >> 4)*4;
#pragma unroll
            for (int i = 0; i < 4; ++i) {
                int t = rb2 + i;
                if (t < ce) {
                    int p   = base + t;
                    float w = gwt[p];
                    dpk[(size_t)p*HID_ + col] = w * (acc[m][n][i] + bias);
                }
            }
        }
    }
}

// out[m][c] = d0[p0][c]+d1[p0][c]+d0[p1][c]+d1[p1][c]   (fixed order)
__global__ __launch_bounds__(256) void combine_kernel(
    const float* __restrict__ dpair, const int* __restrict__ pos,
    float* __restrict__ out)
{
    int idx = blockIdx.x * 256 + threadIdx.x;
    int m   = idx >> 8;
    int c4  = (idx & 255) * 4;
    int p0 = pos[2*m], p1 = pos[2*m+1];
    const float* d0 = dpair;
    const float* d1 = dpair + (size_t)NP_ * HID_;
    float4 a0 = *(const float4*)(d0 + (size_t)p0*HID_ + c4);
    float4 a1 = *(const float4*)(d1 + (size_t)p0*HID_ + c4);
    float4 b0 = *(const float4*)(d0 + (size_t)p1*HID_ + c4);
    float4 b1 = *(const float4*)(d1 + (size_t)p1*HID_ + c4);
    float4 o = make_float4((a0.x+a1.x)+(b0.x+b1.x), (a0.y+a1.y)+(b0.y+b1.y),
                           (a0.z+a1.z)+(b0.z+b1.z), (a0.w+a1.w)+(b0.w+b1.w));
    *(float4*)(out + (size_t)m*HID_ + c4) = o;
}

// ===========================================================================
// FALLBACK (proven round-2 structure) — only if ws_size too small for tier2.
// ===========================================================================
__global__ __launch_bounds__(256) void gemm1_rs_kernel(
    const __hip_bfloat16* __restrict__ xb, const float* __restrict__ w1,
    const float* __restrict__ w1b, const int* __restrict__ gtok,
    const int* __restrict__ cnt, const int* __restrict__ off,
    __hip_bfloat16* __restrict__ h)
{
    const int e  = blockIdx.z;
    const int ce = cnt[e];
    const int t0 = blockIdx.y * 128;
    if (t0 >= ce) return;
    const int n0   = blockIdx.x * 64;
    const int base = off[e];
    const float* w1e = w1 + (size_t)e * (2*FFN_) * HID_;

    __shared__ __align__(16) __hip_bfloat16 As[128*64];
    __shared__ __align__(16) __hip_bfloat16 Bs[128*64];

    const int tid  = threadIdx.x;
    const int lane = tid & 63;
    const int wid  = tid >> 6;
    const int wm   = wid >> 1;
    const int wn   = wid & 1;

    const __hip_bfloat16* asrc[4];
#pragma unroll
    for (int q = 0; q < 4; ++q) {
        int slot = q*256 + tid;
        int r = slot >> 3, p = slot & 7;
        int rr  = min(t0 + r, ce - 1);
        int tok = gtok[base + rr];
        int c = p ^ (r & 7);
        asrc[q] = xb + (size_t)tok * HID_ + c*8;
    }

    const int brow = tid >> 1;
    const int hk   = tid & 1;
    const int q2 = brow >> 5, s = brow & 31;
    const int grow = (q2 & 1) ? (FFN_ + n0 + (q2>>1)*32 + s)
                              : (       n0 + (q2>>1)*32 + s);
    const float* bsrc = w1e + (size_t)grow * HID_ + hk*32;

    f32x4 acc[4][4];
#pragma unroll
    for (int m = 0; m < 4; ++m)
#pragma unroll
        for (int n = 0; n < 4; ++n) acc[m][n] = (f32x4){0.f,0.f,0.f,0.f};

    float4 breg[8];
#pragma unroll
    for (int j = 0; j < 8; ++j) breg[j] = *(const float4*)(bsrc + j*4);

    for (int k0 = 0; k0 < HID_; k0 += 64) {
#pragma unroll
        for (int q = 0; q < 4; ++q) {
            __builtin_amdgcn_global_load_lds(
                (GVOID*)(asrc[q] + k0),
                (LVOID*)(&As[(q*256 + wid*64)*8]), 16, 0, 0);
        }
#pragma unroll
        for (int cc = 0; cc < 4; ++cc) {
            union { bf16x8 v; short s8[8]; } u;
            const float* f0 = (const float*)&breg[2*cc];
#pragma unroll
            for (int j = 0; j < 8; ++j) u.s8[j] = f2bf(f0[j]);
            int c = hk*4 + cc, p = c ^ (brow & 7);
            *(bf16x8*)&Bs[brow*64 + p*8] = u.v;
        }
        __syncthreads();

        if (k0 + 64 < HID_) {
#pragma unroll
            for (int j = 0; j < 8; ++j) breg[j] = *(const float4*)(bsrc + (k0+64) + j*4);
        }

        bf16x8 af[4][2], bfr[4][2];
#pragma unroll
        for (int m = 0; m < 4; ++m)
#pragma unroll
            for (int kk = 0; kk < 2; ++kk) {
                int r = wm*64 + m*16 + (lane & 15);
                int c = kk*4 + (lane >> 4), p = c ^ (r & 7);
                af[m][kk] = *(bf16x8*)&As[r*64 + p*8];
            }
#pragma unroll
        for (int n = 0; n < 4; ++n)
#pragma unroll
            for (int kk = 0; kk < 2; ++kk) {
                int r = wn*64 + n*16 + (lane & 15);
                int c = kk*4 + (lane >> 4), p = c ^ (r & 7);
                bfr[n][kk] = *(bf16x8*)&Bs[r*64 + p*8];
            }
#pragma unroll
        for (int kk = 0; kk < 2; ++kk)
#pragma unroll
            for (int m = 0; m < 4; ++m)
#pragma unroll
                for (int n = 0; n < 4; ++n)
                    acc[m][n] = __builtin_amdgcn_mfma_f32_16x16x32_bf16(
                        af[m][kk], bfr[n][kk], acc[m][n], 0, 0, 0);
        __syncthreads();
    }

    const float* w1be = w1b + e*2*FFN_;
#pragma unroll
    for (int n = 0; n < 2; ++n) {
        int col = n0 + wn*32 + n*16 + (lane & 15);
        float bg = w1be[col];
        float bu = w1be[FFN_ + col];
#pragma unroll
        for (int m = 0; m < 4; ++m) {
            int rb2 = t0 + wm*64 + m*16 + (lane >> 4)*4;
#pragma unroll
            for (int i = 0; i < 4; ++i) {
                int t = rb2 + i;
                if (t < ce) {
                    float g = acc[m][n][i]   + bg;
                    float u = acc[m][n+2][i] + bu;
                    float hv = (g / (1.f + __expf(-g))) * u;
                    h[(size_t)(base + t)*FFN_ + col] = __float2bfloat16(hv);
                }
            }
        }
    }
}

__global__ __launch_bounds__(256) void gemm2_rs_kernel(
    const __hip_bfloat16* __restrict__ h, const float* __restrict__ w2,
    const float* __restrict__ w2b, const int* __restrict__ gtok,
    const float* __restrict__ gwt, const int* __restrict__ cnt,
    const int* __restrict__ off, float* __restrict__ out)
{
    const int e  = blockIdx.z;
    const int ce = cnt[e];
    const int t0 = blockIdx.y * 128;
    if (t0 >= ce) return;
    const int n0   = blockIdx.x * 128;
    const int base = off[e];
    const float* w2e = w2 + (size_t)e * HID_ * FFN_;

    __shared__ __align__(16) __hip_bfloat16 As[128*64];
    __shared__ __align__(16) __hip_bfloat16 Bs[128*64];

    const int tid  = threadIdx.x;
    const int lane = tid & 63;
    const int wid  = tid >> 6;
    const int wm   = wid >> 1;
    const int wn   = wid & 1;

    const __hip_bfloat16* asrc[4];
#pragma unroll
    for (int q = 0; q < 4; ++q) {
        int slot = q*256 + tid;
        int r = slot >> 3, p = slot & 7;
        int rr = min(t0 + r, ce - 1);
        int c = p ^ (r & 7);
        asrc[q] = h + (size_t)(base + rr) * FFN_ + c*8;
    }

    const int brow = tid >> 1;
    const int hk   = tid & 1;
    const float* bsrc = w2e + (size_t)(n0 + brow) * FFN_ + hk*32;

    f32x4 acc[4][4];
#pragma unroll
    for (int m = 0; m < 4; ++m)
#pragma unroll
        for (int n = 0; n < 4; ++n) acc[m][n] = (f32x4){0.f,0.f,0.f,0.f};

    float4 breg[8];
#pragma unroll
    for (int j = 0; j < 8; ++j) breg[j] = *(const float4*)(bsrc + j*4);

    for (int k0 = 0; k0 < FFN_; k0 += 64) {
#pragma unroll
        for (int q = 0; q < 4; ++q) {
            __builtin_amdgcn_global_load_lds(
                (GVOID*)(asrc[q] + k0),
                (LVOID*)(&As[(q*256 + wid*64)*8]), 16, 0, 0);
        }
#pragma unroll
        for (int cc = 0; cc < 4; ++cc) {
            union { bf16x8 v; short s8[8]; } u;
            const float* f0 = (const float*)&breg[2*cc];
#pragma unroll
            for (int j = 0; j < 8; ++j) u.s8[j] = f2bf(f0[j]);
            int c = hk*4 + cc, p = c ^ (brow & 7);
            *(bf16x8*)&Bs[brow*64 + p*8] = u.v;
        }
        __syncthreads();

        if (k0 + 64 < FFN_) {
#pragma unroll
            for (int j = 0; j < 8; ++j) breg[j] = *(const float4*)(bsrc + (k0+64) + j*4);
        }

        bf16x8 af[4][2], bfr[4][2];
#pragma unroll
        for (int m = 0; m < 4; ++m)
#pragma unroll
            for (int kk = 0; kk < 2; ++kk) {
                int r = wm*64 + m*16 + (lane & 15);
                int c = kk*4 + (lane >> 4), p = c ^ (r & 7);
                af[m][kk] = *(bf16x8*)&As[r*64 + p*8];
            }
#pragma unroll
        for (int n = 0; n < 4; ++n)
#pragma unroll
            for (int kk = 0; kk < 2; ++kk) {
                int r = wn*64 + n*16 + (lane & 15);
                int c = kk*4 + (lane >> 4), p = c ^ (r & 7);
                bfr[n][kk] = *(bf16x8*)&Bs[r*64 + p*8];
            }
#pragma unroll
        for (int kk = 0; kk < 2; ++kk)
#pragma unroll
            for (int m = 0; m < 4; ++m)
#pragma unroll
                for (int n = 0; n < 4; ++n)
                    acc[m][n] = __builtin_amdgcn_mfma_f32_16x16x32_bf16(
                        af[m][kk], bfr[n][kk], acc[m][n], 0, 0, 0);
        __syncthreads();
    }

    const float* w2be = w2b + e*HID_;
#pragma unroll
    for (int n = 0; n < 4; ++n) {
        int col = n0 + wn*64 + n*16 + (lane & 15);
        float bias = w2be[col];
#pragma unroll
        for (int m = 0; m < 4; ++m) {
            int rb2 = t0 + wm*64 + m*16 + (lane >> 4)*4;
#pragma unroll
            for (int i = 0; i < 4; ++i) {
                int t = rb2 + i;
                if (t < ce) {
                    int p   = base + t;
                    float w = gwt[p];
                    atomicAdd(&out[(size_t)gtok[p]*HID_ + col], w * (acc[m][n][i] + bias));
                }
            }
        }
    }
}

// ---------------------------------------------------------------------------
extern "C" void kernel_launch(void* const* d_in, const int* in_sizes, int n_in,
                              void* d_out, int out_size, void* d_ws, size_t ws_size,
                              hipStream_t stream)
{
    const float* x   = (const float*)d_in[0];
    const float* rw  = (const float*)d_in[1];
    const float* rb  = (const float*)d_in[2];
    const float* w1  = (const float*)d_in[3];
    const float* w1b = (const float*)d_in[4];
    const float* w2  = (const float*)d_in[5];
    const float* w2b = (const float*)d_in[6];

    float* out      = (float*)d_out;
    float* topk_out = out + (size_t)M_ * HID_;

    char*  ws   = (char*)d_ws;
    int*   ids  = (int*)  (ws);
    float* wts  = (float*)(ws + 16384);
    int*   gtok = (int*)  (ws + 32768);
    float* gwt  = (float*)(ws + 49152);
    int*   cnt  = (int*)  (ws + 65536);
    int*   off  = (int*)  (ws + 65536 + 128);
    int*   fill = (int*)  (ws + 65536 + 256);
    int*   pos  = (int*)  (ws + 98304);

    const size_t MB = 1024*1024;
    __hip_bfloat16* xb    = (__hip_bfloat16*)(ws + 131072);            // 4 MB
    __hip_bfloat16* h     = (__hip_bfloat16*)(ws + 131072 + 4*MB);     // 16 MB
    float*          dpair = (float*)         (ws + 131072 + 20*MB);    // 32 MB
    const bool tier2 = (ws_size >= 131072 + 52*MB);

    hipMemsetAsync(cnt, 0, E_ * sizeof(int), stream);

    router_kernel<<<M_, 64, 0, stream>>>(x, rw, rb, ids, wts, cnt, topk_out, xb);
    offsets_kernel<<<1, 64, 0, stream>>>(cnt, off, fill);
    scatter_kernel<<<M_/256, 256, 0, stream>>>(ids, wts, fill, gtok, gwt, pos);

    if (tier2) {
        dim3 g1(FFN_/64, M_/128, E_);        // (32, 16, 8)
        gemm1_kernel<<<g1, 256, 0, stream>>>(xb, w1, w1b, gtok, cnt, off, h);

        dim3 g2(HID_/128, M_/128, 2*E_);     // (8, 16, 16) split-K=2
        gemm2_kernel<<<g2, 256, 0, stream>>>(h, w2, w2b, gwt, cnt, off, dpair);

        combine_kernel<<<(M_*HID_)/(256*4), 256, 0, stream>>>(dpair, pos, out);
    } else {
        hipMemsetAsync(out, 0, (size_t)M_ * HID_ * sizeof(float), stream);

        dim3 g1(FFN_/64, M_/128, E_);
        gemm1_rs_kernel<<<g1, 256, 0, stream>>>(xb, w1, w1b, gtok, cnt, off, h);

        dim3 g2(HID_/128, M_/128, E_);
        gemm2_rs_kernel<<<g2, 256, 0, stream>>>(h, w2, w2b, gtok, gwt, cnt, off, out);
    }
}

// Round 16
// 229.402 us; speedup vs baseline: 1.0263x; 1.0263x over previous
//
#include <hip/hip_runtime.h>
#include <hip/hip_bf16.h>
#include <math.h>

#define E_    8
#define HID_  1024
#define FFN_  2048
#define M_    2048     // B*S
#define NP_   (M_*2)   // total (token, expert) pairs

typedef __attribute__((ext_vector_type(8))) short bf16x8;
typedef __attribute__((ext_vector_type(8))) short short8v;
typedef __attribute__((ext_vector_type(4))) float f32x4;
typedef __attribute__((ext_vector_type(4))) int   i32x4;

typedef const __attribute__((address_space(1))) void GVOID;
typedef __attribute__((address_space(3))) void LVOID;

#define VMCNT4 asm volatile("s_waitcnt vmcnt(4)" ::: "memory")
#define VMCNT0 asm volatile("s_waitcnt vmcnt(0)" ::: "memory")

__device__ __forceinline__ short f2bf(float f) {
    union { __hip_bfloat16 b; short s; } u;
    u.b = __float2bfloat16(f);
    return u.s;
}

// pack 8 consecutive-k fp32 (two f32x4) into one bf16x8 fragment (RNE)
__device__ __forceinline__ bf16x8 pk8(f32x4 lo, f32x4 hi) {
    unsigned u0, u1, u2, u3;
    asm("v_cvt_pk_bf16_f32 %0, %1, %2" : "=v"(u0) : "v"(lo.x), "v"(lo.y));
    asm("v_cvt_pk_bf16_f32 %0, %1, %2" : "=v"(u1) : "v"(lo.z), "v"(lo.w));
    asm("v_cvt_pk_bf16_f32 %0, %1, %2" : "=v"(u2) : "v"(hi.x), "v"(hi.y));
    asm("v_cvt_pk_bf16_f32 %0, %1, %2" : "=v"(u3) : "v"(hi.z), "v"(hi.w));
    union { i32x4 i; bf16x8 b; } r;
    r.i = (i32x4){(int)u0, (int)u1, (int)u2, (int)u3};
    return r.b;
}

// ---------------------------------------------------------------------------
// Router (+ fused x->bf16 conversion): one wave per token.  [proven]
// ---------------------------------------------------------------------------
__global__ __launch_bounds__(64) void router_kernel(
    const float* __restrict__ x, const float* __restrict__ rw,
    const float* __restrict__ rb, int* __restrict__ ids,
    float* __restrict__ wts, int* __restrict__ cnt,
    float* __restrict__ topk_out, __hip_bfloat16* __restrict__ xb)
{
    const int m    = blockIdx.x;
    const int lane = threadIdx.x;
    const float4* xm4 = (const float4*)(x + (size_t)m * HID_);

    float4 xv[4];
#pragma unroll
    for (int j = 0; j < 4; ++j) xv[j] = xm4[j*64 + lane];

    short4* xbr = (short4*)(xb + (size_t)m * HID_);
#pragma unroll
    for (int j = 0; j < 4; ++j) {
        short4 o;
        o.x = f2bf(xv[j].x); o.y = f2bf(xv[j].y);
        o.z = f2bf(xv[j].z); o.w = f2bf(xv[j].w);
        xbr[j*64 + lane] = o;
    }

    float lg[E_];
#pragma unroll
    for (int e = 0; e < E_; ++e) {
        const float4* we4 = (const float4*)(rw + e * HID_);
        float s = 0.f;
#pragma unroll
        for (int j = 0; j < 4; ++j) {
            float4 w = we4[j*64 + lane];
            s = fmaf(xv[j].x, w.x, s);
            s = fmaf(xv[j].y, w.y, s);
            s = fmaf(xv[j].z, w.z, s);
            s = fmaf(xv[j].w, w.w, s);
        }
        lg[e] = s;
    }
#pragma unroll
    for (int off = 32; off; off >>= 1)
#pragma unroll
        for (int e = 0; e < E_; ++e) lg[e] += __shfl_xor(lg[e], off);

    if (lane == 0) {
        float l2[E_], p[E_];
        float mx = -1e30f;
#pragma unroll
        for (int e = 0; e < E_; ++e) { l2[e] = lg[e] + rb[e]; mx = fmaxf(mx, l2[e]); }
        float sum = 0.f;
#pragma unroll
        for (int e = 0; e < E_; ++e) { p[e] = expf(l2[e] - mx); sum += p[e]; }
        float inv = 1.f / sum;
#pragma unroll
        for (int e = 0; e < E_; ++e) p[e] *= inv;

        int   i1 = -1, i2 = -1;
        float v1 = -1e30f, v2 = -1e30f;
#pragma unroll
        for (int e = 0; e < E_; ++e) {
            float pe = p[e];
            if (pe > v1)      { v2 = v1; i2 = i1; v1 = pe; i1 = e; }
            else if (pe > v2) { v2 = pe; i2 = e; }
        }
        ids[2*m]   = i1;  ids[2*m+1]   = i2;
        wts[2*m]   = v1;  wts[2*m+1]   = v2;
        topk_out[2*m]   = v1;
        topk_out[2*m+1] = v2;
        atomicAdd(&cnt[i1], 1);
        atomicAdd(&cnt[i2], 1);
    }
}

__global__ void offsets_kernel(const int* __restrict__ cnt,
                               int* __restrict__ off, int* __restrict__ fill)
{
    if (threadIdx.x == 0 && blockIdx.x == 0) {
        int acc = 0;
        for (int e = 0; e < E_; ++e) { off[e] = acc; fill[e] = acc; acc += cnt[e]; }
    }
}

__global__ __launch_bounds__(256) void scatter_kernel(
    const int* __restrict__ ids, const float* __restrict__ wts,
    int* __restrict__ fill, int* __restrict__ gtok, float* __restrict__ gwt,
    int* __restrict__ pos)
{
    int m = blockIdx.x * 256 + threadIdx.x;
    if (m >= M_) return;
#pragma unroll
    for (int s = 0; s < 2; ++s) {
        int e = ids[2*m + s];
        int p = atomicAdd(&fill[e], 1);
        gtok[p] = m;
        gwt[p]  = wts[2*m + s];
        pos[2*m + s] = p;
    }
}

// ===========================================================================
// GEMM1 (R14-measured, 115us): B = w1 fp32 staged raw via global_load_lds,
// cvt to bf16 at frag-read (pk8). Double-buffered 48KB, 2-phase schedule.
// z==8 slice: parasitic w2 fp32->bf16 conversion (R13-measured, +9us) so
// gemm2 can use the clean bf16 path with zero serial conversion anywhere.
// ===========================================================================
__global__ __launch_bounds__(256, 3) void gemm1_kernel(
    const __hip_bfloat16* __restrict__ xb, const float* __restrict__ w1,
    const float* __restrict__ w1b, const int* __restrict__ gtok,
    const int* __restrict__ cnt, const int* __restrict__ off,
    __hip_bfloat16* __restrict__ h,
    const float* __restrict__ w2, __hip_bfloat16* __restrict__ w2bf)
{
    if (blockIdx.z == 8) {
        // Parasitic w2 conversion: 512 blocks x 4096 chunks (16 chunks/thread).
        int pb = blockIdx.x + 32 * blockIdx.y;            // 0..511
        const float4* src = (const float4*)w2;
        short8v* dst = (short8v*)w2bf;
        size_t cb0 = (size_t)pb * 4096;
        for (int it = 0; it < 4; ++it) {
            size_t cbase = cb0 + it*1024;
            float4 a[4], b[4];
#pragma unroll
            for (int u = 0; u < 4; ++u) {
                size_t c = cbase + u*256 + threadIdx.x;
                a[u] = src[2*c];
                b[u] = src[2*c + 1];
            }
#pragma unroll
            for (int u = 0; u < 4; ++u) {
                size_t c = cbase + u*256 + threadIdx.x;
                short8v o;
                o[0] = f2bf(a[u].x); o[1] = f2bf(a[u].y);
                o[2] = f2bf(a[u].z); o[3] = f2bf(a[u].w);
                o[4] = f2bf(b[u].x); o[5] = f2bf(b[u].y);
                o[6] = f2bf(b[u].z); o[7] = f2bf(b[u].w);
                dst[c] = o;
            }
        }
        return;
    }

    const int e  = blockIdx.z;
    const int ce = cnt[e];
    const int t0 = blockIdx.y * 128;
    if (t0 >= ce) return;
    const int n0   = blockIdx.x * 64;
    const int base = off[e];
    const float* w1e = w1 + (size_t)e * (2*FFN_) * HID_;

    __shared__ __align__(16) __hip_bfloat16 As[2][128*32];   // 8KB each
    __shared__ __align__(16) float          Bsf[2][128*32];  // 16KB each

    const int tid  = threadIdx.x;
    const int lane = tid & 63;
    const int wid  = tid >> 6;
    const int wm   = wid >> 1;
    const int wn   = wid & 1;
    const int cf   = lane >> 4;

    const __hip_bfloat16* asrc[2];
#pragma unroll
    for (int q = 0; q < 2; ++q) {
        int slot = q*256 + tid;
        int r = slot >> 2, p = slot & 3;
        int c = p ^ ((r >> 1) & 3);
        int rr  = min(t0 + r, ce - 1);
        asrc[q] = xb + (size_t)gtok[base + rr] * HID_ + c*8;
    }
    const float* bsrc[4];
#pragma unroll
    for (int q = 0; q < 4; ++q) {
        int slot = q*256 + tid;
        int r = slot >> 3, p = slot & 7;
        int c = p ^ (r & 7);
        int q2 = r >> 5, s = r & 31;
        int grow = (q2 & 1) ? (FFN_ + n0 + (q2>>1)*32 + s)
                            : (       n0 + (q2>>1)*32 + s);
        bsrc[q] = w1e + (size_t)grow * HID_ + c*4;
    }

    auto STAGE = [&](int b, int k0) {
#pragma unroll
        for (int q = 0; q < 2; ++q)
            __builtin_amdgcn_global_load_lds((GVOID*)(asrc[q] + k0),
                (LVOID*)(&As[b][(q*256 + wid*64)*8]), 16, 0, 0);
#pragma unroll
        for (int q = 0; q < 4; ++q)
            __builtin_amdgcn_global_load_lds((GVOID*)(bsrc[q] + k0),
                (LVOID*)(&Bsf[b][(q*256 + wid*64)*4]), 16, 0, 0);
    };

    f32x4 acc[4][4];
#pragma unroll
    for (int m = 0; m < 4; ++m)
#pragma unroll
        for (int n = 0; n < 4; ++n) acc[m][n] = (f32x4){0.f,0.f,0.f,0.f};

    auto COMPUTE = [&](int cb) {
        bf16x8 af[4], bfr[4];
#pragma unroll
        for (int m = 0; m < 4; ++m) {
            int r = wm*64 + m*16 + (lane & 15);
            int sw = cf ^ ((r >> 1) & 3);
            af[m] = *(bf16x8*)&As[cb][r*32 + sw*8];
        }
#pragma unroll
        for (int n = 0; n < 4; ++n) {
            int r = wn*64 + n*16 + (lane & 15);
            int p0 = (2*cf)     ^ (r & 7);
            int p1 = (2*cf + 1) ^ (r & 7);
            f32x4 lo = *(f32x4*)&Bsf[cb][r*32 + p0*4];
            f32x4 hi = *(f32x4*)&Bsf[cb][r*32 + p1*4];
            bfr[n] = pk8(lo, hi);
        }
        __builtin_amdgcn_s_setprio(1);
#pragma unroll
        for (int m = 0; m < 4; ++m)
#pragma unroll
            for (int n = 0; n < 4; ++n)
                acc[m][n] = __builtin_amdgcn_mfma_f32_16x16x32_bf16(
                    af[m], bfr[n], acc[m][n], 0, 0, 0);
        __builtin_amdgcn_s_setprio(0);
    };

    const int NT = HID_/32;   // 32
    STAGE(0, 0);
    __syncthreads();
    for (int t = 0; t < NT; ++t) {
        int cur = t & 1, nxt = cur ^ 1;
        if (t + 1 < NT) STAGE(nxt, (t+1)*32);
        COMPUTE(cur);
        __syncthreads();
    }

    // Epilogue: fused SiLU(gate)*up -> h (bf16)
    const float* w1be = w1b + e*2*FFN_;
#pragma unroll
    for (int n = 0; n < 2; ++n) {
        int col = n0 + wn*32 + n*16 + (lane & 15);
        float bg = w1be[col];
        float bu = w1be[FFN_ + col];
#pragma unroll
        for (int m = 0; m < 4; ++m) {
            int rb2 = t0 + wm*64 + m*16 + (lane >> 4)*4;
#pragma unroll
            for (int i = 0; i < 4; ++i) {
                int t = rb2 + i;
                if (t < ce) {
                    float g = acc[m][n][i]   + bg;
                    float u = acc[m][n+2][i] + bu;
                    float hv = (g / (1.f + __expf(-g))) * u;
                    h[(size_t)(base + t)*FFN_ + col] = __float2bfloat16(hv);
                }
            }
        }
    }
}

// ===========================================================================
// GEMM2 (R13-measured, bf16 B): 128 pairs x 128 hid cols, split-K=2
// (z = e + 8*ks), TRIPLE-buffered bf16 LDS, depth-2 prefetch, counted
// vmcnt(4). B = w2bf (produced by gemm1's parasite). Plain stores into
// dpair[ks]; combine sums 4 slices.
// ===========================================================================
__global__ __launch_bounds__(256, 3) void gemm2_kernel(
    const __hip_bfloat16* __restrict__ h, const __hip_bfloat16* __restrict__ w2bf,
    const float* __restrict__ w2b, const float* __restrict__ gwt,
    const int* __restrict__ cnt, const int* __restrict__ off,
    float* __restrict__ dpair)
{
    const int e  = blockIdx.z & 7;
    const int ks = blockIdx.z >> 3;
    const int ce = cnt[e];
    const int t0 = blockIdx.y * 128;
    if (t0 >= ce) return;
    const int n0    = blockIdx.x * 128;
    const int base  = off[e];
    const int kbase = ks * (FFN_/2);
    const __hip_bfloat16* w2e = w2bf + (size_t)e * HID_ * FFN_;

    __shared__ __align__(16) __hip_bfloat16 As[3][128*32];
    __shared__ __align__(16) __hip_bfloat16 Bs[3][128*32];

    const int tid  = threadIdx.x;
    const int lane = tid & 63;
    const int wid  = tid >> 6;
    const int wm   = wid >> 1;
    const int wn   = wid & 1;

    const __hip_bfloat16 *asrc[2], *bsrc[2];
#pragma unroll
    for (int q = 0; q < 2; ++q) {
        int slot = q*256 + tid;
        int r = slot >> 2, p = slot & 3;
        int c = p ^ ((r >> 1) & 3);
        int rr = min(t0 + r, ce - 1);
        asrc[q] = h   + (size_t)(base + rr) * FFN_ + kbase + c*8;
        bsrc[q] = w2e + (size_t)(n0 + r)    * FFN_ + kbase + c*8;
    }

    auto STAGE = [&](int b, int k0) {
#pragma unroll
        for (int q = 0; q < 2; ++q)
            __builtin_amdgcn_global_load_lds((GVOID*)(asrc[q] + k0),
                (LVOID*)(&As[b][(q*256 + wid*64)*8]), 16, 0, 0);
#pragma unroll
        for (int q = 0; q < 2; ++q)
            __builtin_amdgcn_global_load_lds((GVOID*)(bsrc[q] + k0),
                (LVOID*)(&Bs[b][(q*256 + wid*64)*8]), 16, 0, 0);
    };

    f32x4 acc[4][4];
#pragma unroll
    for (int m = 0; m < 4; ++m)
#pragma unroll
        for (int n = 0; n < 4; ++n) acc[m][n] = (f32x4){0.f,0.f,0.f,0.f};

    const int cf = lane >> 4;
    auto COMPUTE = [&](int cb) {
        bf16x8 af[4], bfr[4];
#pragma unroll
        for (int m = 0; m < 4; ++m) {
            int r = wm*64 + m*16 + (lane & 15);
            int sw = cf ^ ((r >> 1) & 3);
            af[m] = *(bf16x8*)&As[cb][r*32 + sw*8];
        }
#pragma unroll
        for (int n = 0; n < 4; ++n) {
            int r = wn*64 + n*16 + (lane & 15);
            int sw = cf ^ ((r >> 1) & 3);
            bfr[n] = *(bf16x8*)&Bs[cb][r*32 + sw*8];
        }
        __builtin_amdgcn_s_setprio(1);
#pragma unroll
        for (int m = 0; m < 4; ++m)
#pragma unroll
            for (int n = 0; n < 4; ++n)
                acc[m][n] = __builtin_amdgcn_mfma_f32_16x16x32_bf16(
                    af[m], bfr[n], acc[m][n], 0, 0, 0);
        __builtin_amdgcn_s_setprio(0);
    };

    const int NT = (FFN_/2)/32;   // 32
    STAGE(0, 0);
    STAGE(1, 32);
    VMCNT4;
    __builtin_amdgcn_s_barrier();

    int cb = 0;
    for (int t = 0; t < NT-2; ++t) {
        int sb = cb + 2; if (sb >= 3) sb -= 3;
        STAGE(sb, (t+2)*32);
        COMPUTE(cb);
        VMCNT4;
        __builtin_amdgcn_s_barrier();
        if (++cb == 3) cb = 0;
    }
    COMPUTE(cb);
    VMCNT0;
    __builtin_amdgcn_s_barrier();
    if (++cb == 3) cb = 0;
    COMPUTE(cb);

    const float* w2be = w2b + e*HID_;
    float* dpk = dpair + (size_t)ks * NP_ * HID_;
#pragma unroll
    for (int n = 0; n < 4; ++n) {
        int col = n0 + wn*64 + n*16 + (lane & 15);
        float bias = (ks == 0) ? w2be[col] : 0.f;
#pragma unroll
        for (int m = 0; m < 4; ++m) {
            int rb2 = t0 + wm*64 + m*16 + (lane >> 4)*4;
#pragma unroll
            for (int i = 0; i < 4; ++i) {
                int t = rb2 + i;
                if (t < ce) {
                    int p   = base + t;
                    float w = gwt[p];
                    dpk[(size_t)p*HID_ + col] = w * (acc[m][n][i] + bias);
                }
            }
        }
    }
}

// out[m][c] = d0[p0][c]+d1[p0][c]+d0[p1][c]+d1[p1][c]   (fixed order)
__global__ __launch_bounds__(256) void combine_kernel(
    const float* __restrict__ dpair, const int* __restrict__ pos,
    float* __restrict__ out)
{
    int idx = blockIdx.x * 256 + threadIdx.x;
    int m   = idx >> 8;
    int c4  = (idx & 255) * 4;
    int p0 = pos[2*m], p1 = pos[2*m+1];
    const float* d0 = dpair;
    const float* d1 = dpair + (size_t)NP_ * HID_;
    float4 a0 = *(const float4*)(d0 + (size_t)p0*HID_ + c4);
    float4 a1 = *(const float4*)(d1 + (size_t)p0*HID_ + c4);
    float4 b0 = *(const float4*)(d0 + (size_t)p1*HID_ + c4);
    float4 b1 = *(const float4*)(d1 + (size_t)p1*HID_ + c4);
    float4 o = make_float4((a0.x+a1.x)+(b0.x+b1.x), (a0.y+a1.y)+(b0.y+b1.y),
                           (a0.z+a1.z)+(b0.z+b1.z), (a0.w+a1.w)+(b0.w+b1.w));
    *(float4*)(out + (size_t)m*HID_ + c4) = o;
}

// ===========================================================================
// FALLBACK (proven round-2 structure) — only if ws_size too small for tier2.
// ===========================================================================
__global__ __launch_bounds__(256) void gemm1_rs_kernel(
    const __hip_bfloat16* __restrict__ xb, const float* __restrict__ w1,
    const float* __restrict__ w1b, const int* __restrict__ gtok,
    const int* __restrict__ cnt, const int* __restrict__ off,
    __hip_bfloat16* __restrict__ h)
{
    const int e  = blockIdx.z;
    const int ce = cnt[e];
    const int t0 = blockIdx.y * 128;
    if (t0 >= ce) return;
    const int n0   = blockIdx.x * 64;
    const int base = off[e];
    const float* w1e = w1 + (size_t)e * (2*FFN_) * HID_;

    __shared__ __align__(16) __hip_bfloat16 As[128*64];
    __shared__ __align__(16) __hip_bfloat16 Bs[128*64];

    const int tid  = threadIdx.x;
    const int lane = tid & 63;
    const int wid  = tid >> 6;
    const int wm   = wid >> 1;
    const int wn   = wid & 1;

    const __hip_bfloat16* asrc[4];
#pragma unroll
    for (int q = 0; q < 4; ++q) {
        int slot = q*256 + tid;
        int r = slot >> 3, p = slot & 7;
        int rr  = min(t0 + r, ce - 1);
        int tok = gtok[base + rr];
        int c = p ^ (r & 7);
        asrc[q] = xb + (size_t)tok * HID_ + c*8;
    }

    const int brow = tid >> 1;
    const int hk   = tid & 1;
    const int q2 = brow >> 5, s = brow & 31;
    const int grow = (q2 & 1) ? (FFN_ + n0 + (q2>>1)*32 + s)
                              : (       n0 + (q2>>1)*32 + s);
    const float* bsrc = w1e + (size_t)grow * HID_ + hk*32;

    f32x4 acc[4][4];
#pragma unroll
    for (int m = 0; m < 4; ++m)
#pragma unroll
        for (int n = 0; n < 4; ++n) acc[m][n] = (f32x4){0.f,0.f,0.f,0.f};

    float4 breg[8];
#pragma unroll
    for (int j = 0; j < 8; ++j) breg[j] = *(const float4*)(bsrc + j*4);

    for (int k0 = 0; k0 < HID_; k0 += 64) {
#pragma unroll
        for (int q = 0; q < 4; ++q) {
            __builtin_amdgcn_global_load_lds(
                (GVOID*)(asrc[q] + k0),
                (LVOID*)(&As[(q*256 + wid*64)*8]), 16, 0, 0);
        }
#pragma unroll
        for (int cc = 0; cc < 4; ++cc) {
            union { bf16x8 v; short s8[8]; } u;
            const float* f0 = (const float*)&breg[2*cc];
#pragma unroll
            for (int j = 0; j < 8; ++j) u.s8[j] = f2bf(f0[j]);
            int c = hk*4 + cc, p = c ^ (brow & 7);
            *(bf16x8*)&Bs[brow*64 + p*8] = u.v;
        }
        __syncthreads();

        if (k0 + 64 < HID_) {
#pragma unroll
            for (int j = 0; j < 8; ++j) breg[j] = *(const float4*)(bsrc + (k0+64) + j*4);
        }

        bf16x8 af[4][2], bfr[4][2];
#pragma unroll
        for (int m = 0; m < 4; ++m)
#pragma unroll
            for (int kk = 0; kk < 2; ++kk) {
                int r = wm*64 + m*16 + (lane & 15);
                int c = kk*4 + (lane >> 4), p = c ^ (r & 7);
                af[m][kk] = *(bf16x8*)&As[r*64 + p*8];
            }
#pragma unroll
        for (int n = 0; n < 4; ++n)
#pragma unroll
            for (int kk = 0; kk < 2; ++kk) {
                int r = wn*64 + n*16 + (lane & 15);
                int c = kk*4 + (lane >> 4), p = c ^ (r & 7);
                bfr[n][kk] = *(bf16x8*)&Bs[r*64 + p*8];
            }
#pragma unroll
        for (int kk = 0; kk < 2; ++kk)
#pragma unroll
            for (int m = 0; m < 4; ++m)
#pragma unroll
                for (int n = 0; n < 4; ++n)
                    acc[m][n] = __builtin_amdgcn_mfma_f32_16x16x32_bf16(
                        af[m][kk], bfr[n][kk], acc[m][n], 0, 0, 0);
        __syncthreads();
    }

    const float* w1be = w1b + e*2*FFN_;
#pragma unroll
    for (int n = 0; n < 2; ++n) {
        int col = n0 + wn*32 + n*16 + (lane & 15);
        float bg = w1be[col];
        float bu = w1be[FFN_ + col];
#pragma unroll
        for (int m = 0; m < 4; ++m) {
            int rb2 = t0 + wm*64 + m*16 + (lane >> 4)*4;
#pragma unroll
            for (int i = 0; i < 4; ++i) {
                int t = rb2 + i;
                if (t < ce) {
                    float g = acc[m][n][i]   + bg;
                    float u = acc[m][n+2][i] + bu;
                    float hv = (g / (1.f + __expf(-g))) * u;
                    h[(size_t)(base + t)*FFN_ + col] = __float2bfloat16(hv);
                }
            }
        }
    }
}

__global__ __launch_bounds__(256) void gemm2_rs_kernel(
    const __hip_bfloat16* __restrict__ h, const float* __restrict__ w2,
    const float* __restrict__ w2b, const int* __restrict__ gtok,
    const float* __restrict__ gwt, const int* __restrict__ cnt,
    const int* __restrict__ off, float* __restrict__ out)
{
    const int e  = blockIdx.z;
    const int ce = cnt[e];
    const int t0 = blockIdx.y * 128;
    if (t0 >= ce) return;
    const int n0   = blockIdx.x * 128;
    const int base = off[e];
    const float* w2e = w2 + (size_t)e * HID_ * FFN_;

    __shared__ __align__(16) __hip_bfloat16 As[128*64];
    __shared__ __align__(16) __hip_bfloat16 Bs[128*64];

    const int tid  = threadIdx.x;
    const int lane = tid & 63;
    const int wid  = tid >> 6;
    const int wm   = wid >> 1;
    const int wn   = wid & 1;

    const __hip_bfloat16* asrc[4];
#pragma unroll
    for (int q = 0; q < 4; ++q) {
        int slot = q*256 + tid;
        int r = slot >> 3, p = slot & 7;
        int rr = min(t0 + r, ce - 1);
        int c = p ^ (r & 7);
        asrc[q] = h + (size_t)(base + rr) * FFN_ + c*8;
    }

    const int brow = tid >> 1;
    const int hk   = tid & 1;
    const float* bsrc = w2e + (size_t)(n0 + brow) * FFN_ + hk*32;

    f32x4 acc[4][4];
#pragma unroll
    for (int m = 0; m < 4; ++m)
#pragma unroll
        for (int n = 0; n < 4; ++n) acc[m][n] = (f32x4){0.f,0.f,0.f,0.f};

    float4 breg[8];
#pragma unroll
    for (int j = 0; j < 8; ++j) breg[j] = *(const float4*)(bsrc + j*4);

    for (int k0 = 0; k0 < FFN_; k0 += 64) {
#pragma unroll
        for (int q = 0; q < 4; ++q) {
            __builtin_amdgcn_global_load_lds(
                (GVOID*)(asrc[q] + k0),
                (LVOID*)(&As[(q*256 + wid*64)*8]), 16, 0, 0);
        }
#pragma unroll
        for (int cc = 0; cc < 4; ++cc) {
            union { bf16x8 v; short s8[8]; } u;
            const float* f0 = (const float*)&breg[2*cc];
#pragma unroll
            for (int j = 0; j < 8; ++j) u.s8[j] = f2bf(f0[j]);
            int c = hk*4 + cc, p = c ^ (brow & 7);
            *(bf16x8*)&Bs[brow*64 + p*8] = u.v;
        }
        __syncthreads();

        if (k0 + 64 < FFN_) {
#pragma unroll
            for (int j = 0; j < 8; ++j) breg[j] = *(const float4*)(bsrc + (k0+64) + j*4);
        }

        bf16x8 af[4][2], bfr[4][2];
#pragma unroll
        for (int m = 0; m < 4; ++m)
#pragma unroll
            for (int kk = 0; kk < 2; ++kk) {
                int r = wm*64 + m*16 + (lane & 15);
                int c = kk*4 + (lane >> 4), p = c ^ (r & 7);
                af[m][kk] = *(bf16x8*)&As[r*64 + p*8];
            }
#pragma unroll
        for (int n = 0; n < 4; ++n)
#pragma unroll
            for (int kk = 0; kk < 2; ++kk) {
                int r = wn*64 + n*16 + (lane & 15);
                int c = kk*4 + (lane >> 4), p = c ^ (r & 7);
                bfr[n][kk] = *(bf16x8*)&Bs[r*64 + p*8];
            }
#pragma unroll
        for (int kk = 0; kk < 2; ++kk)
#pragma unroll
            for (int m = 0; m < 4; ++m)
#pragma unroll
                for (int n = 0; n < 4; ++n)
                    acc[m][n] = __builtin_amdgcn_mfma_f32_16x16x32_bf16(
                        af[m][kk], bfr[n][kk], acc[m][n], 0, 0, 0);
        __syncthreads();
    }

    const float* w2be = w2b + e*HID_;
#pragma unroll
    for (int n = 0; n < 4; ++n) {
        int col = n0 + wn*64 + n*16 + (lane & 15);
        float bias = w2be[col];
#pragma unroll
        for (int m = 0; m < 4; ++m) {
            int rb2 = t0 + wm*64 + m*16 + (lane >> 4)*4;
#pragma unroll
            for (int i = 0; i < 4; ++i) {
                int t = rb2 + i;
                if (t < ce) {
                    int p   = base + t;
                    float w = gwt[p];
                    atomicAdd(&out[(size_t)gtok[p]*HID_ + col], w * (acc[m][n][i] + bias));
                }
            }
        }
    }
}

// ---------------------------------------------------------------------------
extern "C" void kernel_launch(void* const* d_in, const int* in_sizes, int n_in,
                              void* d_out, int out_size, void* d_ws, size_t ws_size,
                              hipStream_t stream)
{
    const float* x   = (const float*)d_in[0];
    const float* rw  = (const float*)d_in[1];
    const float* rb  = (const float*)d_in[2];
    const float* w1  = (const float*)d_in[3];
    const float* w1b = (const float*)d_in[4];
    const float* w2  = (const float*)d_in[5];
    const float* w2b = (const float*)d_in[6];

    float* out      = (float*)d_out;
    float* topk_out = out + (size_t)M_ * HID_;

    char*  ws   = (char*)d_ws;
    int*   ids  = (int*)  (ws);
    float* wts  = (float*)(ws + 16384);
    int*   gtok = (int*)  (ws + 32768);
    float* gwt  = (float*)(ws + 49152);
    int*   cnt  = (int*)  (ws + 65536);
    int*   off  = (int*)  (ws + 65536 + 128);
    int*   fill = (int*)  (ws + 65536 + 256);
    int*   pos  = (int*)  (ws + 98304);

    const size_t MB = 1024*1024;
    __hip_bfloat16* xb    = (__hip_bfloat16*)(ws + 131072);            // 4 MB
    __hip_bfloat16* h     = (__hip_bfloat16*)(ws + 131072 + 4*MB);     // 16 MB
    float*          dpair = (float*)         (ws + 131072 + 20*MB);    // 32 MB
    __hip_bfloat16* w2bf  = (__hip_bfloat16*)(ws + 131072 + 52*MB);    // 32 MB
    const bool tier2 = (ws_size >= 131072 + 84*MB);

    hipMemsetAsync(cnt, 0, E_ * sizeof(int), stream);

    router_kernel<<<M_, 64, 0, stream>>>(x, rw, rb, ids, wts, cnt, topk_out, xb);
    offsets_kernel<<<1, 64, 0, stream>>>(cnt, off, fill);
    scatter_kernel<<<M_/256, 256, 0, stream>>>(ids, wts, fill, gtok, gwt, pos);

    if (tier2) {
        dim3 g1(FFN_/64, M_/128, E_ + 1);    // (32, 16, 9): z=8 converts w2
        gemm1_kernel<<<g1, 256, 0, stream>>>(xb, w1, w1b, gtok, cnt, off, h,
                                             w2, w2bf);

        dim3 g2(HID_/128, M_/128, 2*E_);     // (8, 16, 16) split-K=2
        gemm2_kernel<<<g2, 256, 0, stream>>>(h, w2bf, w2b, gwt, cnt, off, dpair);

        combine_kernel<<<(M_*HID_)/(256*4), 256, 0, stream>>>(dpair, pos, out);
    } else {
        hipMemsetAsync(out, 0, (size_t)M_ * HID_ * sizeof(float), stream);

        dim3 g1(FFN_/64, M_/128, E_);
        gemm1_rs_kernel<<<g1, 256, 0, stream>>>(xb, w1, w1b, gtok, cnt, off, h);

        dim3 g2(HID_/128, M_/128, E_);
        gemm2_rs_kernel<<<g2, 256, 0, stream>>>(h, w2, w2b, gtok, gwt, cnt, off, out);
    }
}

// Round 17
// 210.899 us; speedup vs baseline: 1.1163x; 1.0877x over previous
//
#include <hip/hip_runtime.h>
#include <hip/hip_bf16.h>
#include <math.h>

#define E_    8
#define HID_  1024
#define FFN_  2048
#define M_    2048     // B*S
#define NP2_  (E_*M_)  // fixed-capacity pair slots (2048 per expert)

typedef __attribute__((ext_vector_type(8))) short bf16x8;
typedef __attribute__((ext_vector_type(8))) short short8v;
typedef __attribute__((ext_vector_type(4))) float f32x4;
typedef __attribute__((ext_vector_type(4))) int   i32x4;

typedef const __attribute__((address_space(1))) void GVOID;
typedef __attribute__((address_space(3))) void LVOID;

#define VMCNT4 asm volatile("s_waitcnt vmcnt(4)" ::: "memory")
#define VMCNT0 asm volatile("s_waitcnt vmcnt(0)" ::: "memory")

__device__ __forceinline__ short f2bf(float f) {
    union { __hip_bfloat16 b; short s; } u;
    u.b = __float2bfloat16(f);
    return u.s;
}

// pack 8 consecutive-k fp32 (two f32x4) into one bf16x8 fragment (RNE)
__device__ __forceinline__ bf16x8 pk8(f32x4 lo, f32x4 hi) {
    unsigned u0, u1, u2, u3;
    asm("v_cvt_pk_bf16_f32 %0, %1, %2" : "=v"(u0) : "v"(lo.x), "v"(lo.y));
    asm("v_cvt_pk_bf16_f32 %0, %1, %2" : "=v"(u1) : "v"(lo.z), "v"(lo.w));
    asm("v_cvt_pk_bf16_f32 %0, %1, %2" : "=v"(u2) : "v"(hi.x), "v"(hi.y));
    asm("v_cvt_pk_bf16_f32 %0, %1, %2" : "=v"(u3) : "v"(hi.z), "v"(hi.w));
    union { i32x4 i; bf16x8 b; } r;
    r.i = (i32x4){(int)u0, (int)u1, (int)u2, (int)u3};
    return r.b;
}

// ---------------------------------------------------------------------------
// Router with INLINE scatter (fixed-capacity per-expert slots: base = e*M_).
// Also fuses x->bf16. Replaces router+offsets+scatter (3 launches -> 1).
// ---------------------------------------------------------------------------
__global__ __launch_bounds__(64) void router_kernel(
    const float* __restrict__ x, const float* __restrict__ rw,
    const float* __restrict__ rb, int* __restrict__ fill,
    int* __restrict__ gtok, float* __restrict__ gwt, int* __restrict__ pos,
    float* __restrict__ topk_out, __hip_bfloat16* __restrict__ xb)
{
    const int m    = blockIdx.x;
    const int lane = threadIdx.x;
    const float4* xm4 = (const float4*)(x + (size_t)m * HID_);

    float4 xv[4];
#pragma unroll
    for (int j = 0; j < 4; ++j) xv[j] = xm4[j*64 + lane];

    short4* xbr = (short4*)(xb + (size_t)m * HID_);
#pragma unroll
    for (int j = 0; j < 4; ++j) {
        short4 o;
        o.x = f2bf(xv[j].x); o.y = f2bf(xv[j].y);
        o.z = f2bf(xv[j].z); o.w = f2bf(xv[j].w);
        xbr[j*64 + lane] = o;
    }

    float lg[E_];
#pragma unroll
    for (int e = 0; e < E_; ++e) {
        const float4* we4 = (const float4*)(rw + e * HID_);
        float s = 0.f;
#pragma unroll
        for (int j = 0; j < 4; ++j) {
            float4 w = we4[j*64 + lane];
            s = fmaf(xv[j].x, w.x, s);
            s = fmaf(xv[j].y, w.y, s);
            s = fmaf(xv[j].z, w.z, s);
            s = fmaf(xv[j].w, w.w, s);
        }
        lg[e] = s;
    }
#pragma unroll
    for (int off = 32; off; off >>= 1)
#pragma unroll
        for (int e = 0; e < E_; ++e) lg[e] += __shfl_xor(lg[e], off);

    if (lane == 0) {
        float l2[E_], p[E_];
        float mx = -1e30f;
#pragma unroll
        for (int e = 0; e < E_; ++e) { l2[e] = lg[e] + rb[e]; mx = fmaxf(mx, l2[e]); }
        float sum = 0.f;
#pragma unroll
        for (int e = 0; e < E_; ++e) { p[e] = expf(l2[e] - mx); sum += p[e]; }
        float inv = 1.f / sum;
#pragma unroll
        for (int e = 0; e < E_; ++e) p[e] *= inv;

        int   i1 = -1, i2 = -1;
        float v1 = -1e30f, v2 = -1e30f;
#pragma unroll
        for (int e = 0; e < E_; ++e) {
            float pe = p[e];
            if (pe > v1)      { v2 = v1; i2 = i1; v1 = pe; i1 = e; }
            else if (pe > v2) { v2 = pe; i2 = e; }
        }
        topk_out[2*m]   = v1;
        topk_out[2*m+1] = v2;
        // inline scatter into fixed-capacity slots
        int p1s = atomicAdd(&fill[i1], 1);
        int s1  = i1*M_ + p1s;
        gtok[s1] = m; gwt[s1] = v1; pos[2*m]   = s1;
        int p2s = atomicAdd(&fill[i2], 1);
        int s2  = i2*M_ + p2s;
        gtok[s2] = m; gwt[s2] = v2; pos[2*m+1] = s2;
    }
}

// ===========================================================================
// GEMM1 (R16 body): B = w1 fp32 staged raw via global_load_lds, cvt at
// frag-read (pk8). Double-buffered 48KB, 2-phase. z==8: parasitic w2 cvt.
// Fixed-capacity: base = e*M_, ce = fill[e].
// ===========================================================================
__global__ __launch_bounds__(256, 3) void gemm1_kernel(
    const __hip_bfloat16* __restrict__ xb, const float* __restrict__ w1,
    const float* __restrict__ w1b, const int* __restrict__ gtok,
    const int* __restrict__ fill, __hip_bfloat16* __restrict__ h,
    const float* __restrict__ w2, __hip_bfloat16* __restrict__ w2bf)
{
    if (blockIdx.z == 8) {
        int pb = blockIdx.x + 32 * blockIdx.y;            // 0..511
        const float4* src = (const float4*)w2;
        short8v* dst = (short8v*)w2bf;
        size_t cb0 = (size_t)pb * 4096;
        for (int it = 0; it < 4; ++it) {
            size_t cbase = cb0 + it*1024;
            float4 a[4], b[4];
#pragma unroll
            for (int u = 0; u < 4; ++u) {
                size_t c = cbase + u*256 + threadIdx.x;
                a[u] = src[2*c];
                b[u] = src[2*c + 1];
            }
#pragma unroll
            for (int u = 0; u < 4; ++u) {
                size_t c = cbase + u*256 + threadIdx.x;
                short8v o;
                o[0] = f2bf(a[u].x); o[1] = f2bf(a[u].y);
                o[2] = f2bf(a[u].z); o[3] = f2bf(a[u].w);
                o[4] = f2bf(b[u].x); o[5] = f2bf(b[u].y);
                o[6] = f2bf(b[u].z); o[7] = f2bf(b[u].w);
                dst[c] = o;
            }
        }
        return;
    }

    const int e  = blockIdx.z;
    const int ce = fill[e];
    const int t0 = blockIdx.y * 128;
    if (t0 >= ce) return;
    const int n0   = blockIdx.x * 64;
    const int base = e * M_;
    const float* w1e = w1 + (size_t)e * (2*FFN_) * HID_;

    __shared__ __align__(16) __hip_bfloat16 As[2][128*32];   // 8KB each
    __shared__ __align__(16) float          Bsf[2][128*32];  // 16KB each

    const int tid  = threadIdx.x;
    const int lane = tid & 63;
    const int wid  = tid >> 6;
    const int wm   = wid >> 1;
    const int wn   = wid & 1;
    const int cf   = lane >> 4;

    const __hip_bfloat16* asrc[2];
#pragma unroll
    for (int q = 0; q < 2; ++q) {
        int slot = q*256 + tid;
        int r = slot >> 2, p = slot & 3;
        int c = p ^ ((r >> 1) & 3);
        int rr  = min(t0 + r, ce - 1);
        asrc[q] = xb + (size_t)gtok[base + rr] * HID_ + c*8;
    }
    const float* bsrc[4];
#pragma unroll
    for (int q = 0; q < 4; ++q) {
        int slot = q*256 + tid;
        int r = slot >> 3, p = slot & 7;
        int c = p ^ (r & 7);
        int q2 = r >> 5, s = r & 31;
        int grow = (q2 & 1) ? (FFN_ + n0 + (q2>>1)*32 + s)
                            : (       n0 + (q2>>1)*32 + s);
        bsrc[q] = w1e + (size_t)grow * HID_ + c*4;
    }

    auto STAGE = [&](int b, int k0) {
#pragma unroll
        for (int q = 0; q < 2; ++q)
            __builtin_amdgcn_global_load_lds((GVOID*)(asrc[q] + k0),
                (LVOID*)(&As[b][(q*256 + wid*64)*8]), 16, 0, 0);
#pragma unroll
        for (int q = 0; q < 4; ++q)
            __builtin_amdgcn_global_load_lds((GVOID*)(bsrc[q] + k0),
                (LVOID*)(&Bsf[b][(q*256 + wid*64)*4]), 16, 0, 0);
    };

    f32x4 acc[4][4];
#pragma unroll
    for (int m = 0; m < 4; ++m)
#pragma unroll
        for (int n = 0; n < 4; ++n) acc[m][n] = (f32x4){0.f,0.f,0.f,0.f};

    auto COMPUTE = [&](int cb) {
        bf16x8 af[4], bfr[4];
#pragma unroll
        for (int m = 0; m < 4; ++m) {
            int r = wm*64 + m*16 + (lane & 15);
            int sw = cf ^ ((r >> 1) & 3);
            af[m] = *(bf16x8*)&As[cb][r*32 + sw*8];
        }
#pragma unroll
        for (int n = 0; n < 4; ++n) {
            int r = wn*64 + n*16 + (lane & 15);
            int p0 = (2*cf)     ^ (r & 7);
            int p1 = (2*cf + 1) ^ (r & 7);
            f32x4 lo = *(f32x4*)&Bsf[cb][r*32 + p0*4];
            f32x4 hi = *(f32x4*)&Bsf[cb][r*32 + p1*4];
            bfr[n] = pk8(lo, hi);
        }
        __builtin_amdgcn_s_setprio(1);
#pragma unroll
        for (int m = 0; m < 4; ++m)
#pragma unroll
            for (int n = 0; n < 4; ++n)
                acc[m][n] = __builtin_amdgcn_mfma_f32_16x16x32_bf16(
                    af[m], bfr[n], acc[m][n], 0, 0, 0);
        __builtin_amdgcn_s_setprio(0);
    };

    const int NT = HID_/32;   // 32
    STAGE(0, 0);
    __syncthreads();
    for (int t = 0; t < NT; ++t) {
        int cur = t & 1, nxt = cur ^ 1;
        if (t + 1 < NT) STAGE(nxt, (t+1)*32);
        COMPUTE(cur);
        __syncthreads();
    }

    // Epilogue: fused SiLU(gate)*up -> h (bf16)
    const float* w1be = w1b + e*2*FFN_;
#pragma unroll
    for (int n = 0; n < 2; ++n) {
        int col = n0 + wn*32 + n*16 + (lane & 15);
        float bg = w1be[col];
        float bu = w1be[FFN_ + col];
#pragma unroll
        for (int m = 0; m < 4; ++m) {
            int rb2 = t0 + wm*64 + m*16 + (lane >> 4)*4;
#pragma unroll
            for (int i = 0; i < 4; ++i) {
                int t = rb2 + i;
                if (t < ce) {
                    float g = acc[m][n][i]   + bg;
                    float u = acc[m][n+2][i] + bu;
                    float hv = (g / (1.f + __expf(-g))) * u;
                    h[(size_t)(base + t)*FFN_ + col] = __float2bfloat16(hv);
                }
            }
        }
    }
}

// ===========================================================================
// GEMM2 (R16 body, bf16 B from parasite): split-K=2, triple-buffered,
// counted vmcnt(4). Fixed-capacity: base = e*M_, ce = fill[e].
// ===========================================================================
__global__ __launch_bounds__(256, 3) void gemm2_kernel(
    const __hip_bfloat16* __restrict__ h, const __hip_bfloat16* __restrict__ w2bf,
    const float* __restrict__ w2b, const float* __restrict__ gwt,
    const int* __restrict__ fill, float* __restrict__ dpair)
{
    const int e  = blockIdx.z & 7;
    const int ks = blockIdx.z >> 3;
    const int ce = fill[e];
    const int t0 = blockIdx.y * 128;
    if (t0 >= ce) return;
    const int n0    = blockIdx.x * 128;
    const int base  = e * M_;
    const int kbase = ks * (FFN_/2);
    const __hip_bfloat16* w2e = w2bf + (size_t)e * HID_ * FFN_;

    __shared__ __align__(16) __hip_bfloat16 As[3][128*32];
    __shared__ __align__(16) __hip_bfloat16 Bs[3][128*32];

    const int tid  = threadIdx.x;
    const int lane = tid & 63;
    const int wid  = tid >> 6;
    const int wm   = wid >> 1;
    const int wn   = wid & 1;

    const __hip_bfloat16 *asrc[2], *bsrc[2];
#pragma unroll
    for (int q = 0; q < 2; ++q) {
        int slot = q*256 + tid;
        int r = slot >> 2, p = slot & 3;
        int c = p ^ ((r >> 1) & 3);
        int rr = min(t0 + r, ce - 1);
        asrc[q] = h   + (size_t)(base + rr) * FFN_ + kbase + c*8;
        bsrc[q] = w2e + (size_t)(n0 + r)    * FFN_ + kbase + c*8;
    }

    auto STAGE = [&](int b, int k0) {
#pragma unroll
        for (int q = 0; q < 2; ++q)
            __builtin_amdgcn_global_load_lds((GVOID*)(asrc[q] + k0),
                (LVOID*)(&As[b][(q*256 + wid*64)*8]), 16, 0, 0);
#pragma unroll
        for (int q = 0; q < 2; ++q)
            __builtin_amdgcn_global_load_lds((GVOID*)(bsrc[q] + k0),
                (LVOID*)(&Bs[b][(q*256 + wid*64)*8]), 16, 0, 0);
    };

    f32x4 acc[4][4];
#pragma unroll
    for (int m = 0; m < 4; ++m)
#pragma unroll
        for (int n = 0; n < 4; ++n) acc[m][n] = (f32x4){0.f,0.f,0.f,0.f};

    const int cf = lane >> 4;
    auto COMPUTE = [&](int cb) {
        bf16x8 af[4], bfr[4];
#pragma unroll
        for (int m = 0; m < 4; ++m) {
            int r = wm*64 + m*16 + (lane & 15);
            int sw = cf ^ ((r >> 1) & 3);
            af[m] = *(bf16x8*)&As[cb][r*32 + sw*8];
        }
#pragma unroll
        for (int n = 0; n < 4; ++n) {
            int r = wn*64 + n*16 + (lane & 15);
            int sw = cf ^ ((r >> 1) & 3);
            bfr[n] = *(bf16x8*)&Bs[cb][r*32 + sw*8];
        }
        __builtin_amdgcn_s_setprio(1);
#pragma unroll
        for (int m = 0; m < 4; ++m)
#pragma unroll
            for (int n = 0; n < 4; ++n)
                acc[m][n] = __builtin_amdgcn_mfma_f32_16x16x32_bf16(
                    af[m], bfr[n], acc[m][n], 0, 0, 0);
        __builtin_amdgcn_s_setprio(0);
    };

    const int NT = (FFN_/2)/32;   // 32
    STAGE(0, 0);
    STAGE(1, 32);
    VMCNT4;
    __builtin_amdgcn_s_barrier();

    int cb = 0;
    for (int t = 0; t < NT-2; ++t) {
        int sb = cb + 2; if (sb >= 3) sb -= 3;
        STAGE(sb, (t+2)*32);
        COMPUTE(cb);
        VMCNT4;
        __builtin_amdgcn_s_barrier();
        if (++cb == 3) cb = 0;
    }
    COMPUTE(cb);
    VMCNT0;
    __builtin_amdgcn_s_barrier();
    if (++cb == 3) cb = 0;
    COMPUTE(cb);

    const float* w2be = w2b + e*HID_;
    float* dpk = dpair + (size_t)ks * NP2_ * HID_;
#pragma unroll
    for (int n = 0; n < 4; ++n) {
        int col = n0 + wn*64 + n*16 + (lane & 15);
        float bias = (ks == 0) ? w2be[col] : 0.f;
#pragma unroll
        for (int m = 0; m < 4; ++m) {
            int rb2 = t0 + wm*64 + m*16 + (lane >> 4)*4;
#pragma unroll
            for (int i = 0; i < 4; ++i) {
                int t = rb2 + i;
                if (t < ce) {
                    int p   = base + t;
                    float w = gwt[p];
                    dpk[(size_t)p*HID_ + col] = w * (acc[m][n][i] + bias);
                }
            }
        }
    }
}

// out[m][c] = d0[p0][c]+d1[p0][c]+d0[p1][c]+d1[p1][c]   (fixed order)
__global__ __launch_bounds__(256) void combine_kernel(
    const float* __restrict__ dpair, const int* __restrict__ pos,
    float* __restrict__ out)
{
    int idx = blockIdx.x * 256 + threadIdx.x;
    int m   = idx >> 8;
    int c4  = (idx & 255) * 4;
    int p0 = pos[2*m], p1 = pos[2*m+1];
    const float* d0 = dpair;
    const float* d1 = dpair + (size_t)NP2_ * HID_;
    float4 a0 = *(const float4*)(d0 + (size_t)p0*HID_ + c4);
    float4 a1 = *(const float4*)(d1 + (size_t)p0*HID_ + c4);
    float4 b0 = *(const float4*)(d0 + (size_t)p1*HID_ + c4);
    float4 b1 = *(const float4*)(d1 + (size_t)p1*HID_ + c4);
    float4 o = make_float4((a0.x+a1.x)+(b0.x+b1.x), (a0.y+a1.y)+(b0.y+b1.y),
                           (a0.z+a1.z)+(b0.z+b1.z), (a0.w+a1.w)+(b0.w+b1.w));
    *(float4*)(out + (size_t)m*HID_ + c4) = o;
}

// ===========================================================================
// FALLBACK (fixed-capacity variants of proven round-2 structure) — only if
// ws_size too small for tier2 (needs just xb + h = 68 MB + small).
// ===========================================================================
__global__ __launch_bounds__(256) void gemm1_rs_kernel(
    const __hip_bfloat16* __restrict__ xb, const float* __restrict__ w1,
    const float* __restrict__ w1b, const int* __restrict__ gtok,
    const int* __restrict__ fill, __hip_bfloat16* __restrict__ h)
{
    const int e  = blockIdx.z;
    const int ce = fill[e];
    const int t0 = blockIdx.y * 128;
    if (t0 >= ce) return;
    const int n0   = blockIdx.x * 64;
    const int base = e * M_;
    const float* w1e = w1 + (size_t)e * (2*FFN_) * HID_;

    __shared__ __align__(16) __hip_bfloat16 As[128*64];
    __shared__ __align__(16) __hip_bfloat16 Bs[128*64];

    const int tid  = threadIdx.x;
    const int lane = tid & 63;
    const int wid  = tid >> 6;
    const int wm   = wid >> 1;
    const int wn   = wid & 1;

    const __hip_bfloat16* asrc[4];
#pragma unroll
    for (int q = 0; q < 4; ++q) {
        int slot = q*256 + tid;
        int r = slot >> 3, p = slot & 7;
        int rr  = min(t0 + r, ce - 1);
        int tok = gtok[base + rr];
        int c = p ^ (r & 7);
        asrc[q] = xb + (size_t)tok * HID_ + c*8;
    }

    const int brow = tid >> 1;
    const int hk   = tid & 1;
    const int q2 = brow >> 5, s = brow & 31;
    const int grow = (q2 & 1) ? (FFN_ + n0 + (q2>>1)*32 + s)
                              : (       n0 + (q2>>1)*32 + s);
    const float* bsrc = w1e + (size_t)grow * HID_ + hk*32;

    f32x4 acc[4][4];
#pragma unroll
    for (int m = 0; m < 4; ++m)
#pragma unroll
        for (int n = 0; n < 4; ++n) acc[m][n] = (f32x4){0.f,0.f,0.f,0.f};

    float4 breg[8];
#pragma unroll
    for (int j = 0; j < 8; ++j) breg[j] = *(const float4*)(bsrc + j*4);

    for (int k0 = 0; k0 < HID_; k0 += 64) {
#pragma unroll
        for (int q = 0; q < 4; ++q) {
            __builtin_amdgcn_global_load_lds(
                (GVOID*)(asrc[q] + k0),
                (LVOID*)(&As[(q*256 + wid*64)*8]), 16, 0, 0);
        }
#pragma unroll
        for (int cc = 0; cc < 4; ++cc) {
            union { bf16x8 v; short s8[8]; } u;
            const float* f0 = (const float*)&breg[2*cc];
#pragma unroll
            for (int j = 0; j < 8; ++j) u.s8[j] = f2bf(f0[j]);
            int c = hk*4 + cc, p = c ^ (brow & 7);
            *(bf16x8*)&Bs[brow*64 + p*8] = u.v;
        }
        __syncthreads();

        if (k0 + 64 < HID_) {
#pragma unroll
            for (int j = 0; j < 8; ++j) breg[j] = *(const float4*)(bsrc + (k0+64) + j*4);
        }

        bf16x8 af[4][2], bfr[4][2];
#pragma unroll
        for (int m = 0; m < 4; ++m)
#pragma unroll
            for (int kk = 0; kk < 2; ++kk) {
                int r = wm*64 + m*16 + (lane & 15);
                int c = kk*4 + (lane >> 4), p = c ^ (r & 7);
                af[m][kk] = *(bf16x8*)&As[r*64 + p*8];
            }
#pragma unroll
        for (int n = 0; n < 4; ++n)
#pragma unroll
            for (int kk = 0; kk < 2; ++kk) {
                int r = wn*64 + n*16 + (lane & 15);
                int c = kk*4 + (lane >> 4), p = c ^ (r & 7);
                bfr[n][kk] = *(bf16x8*)&Bs[r*64 + p*8];
            }
#pragma unroll
        for (int kk = 0; kk < 2; ++kk)
#pragma unroll
            for (int m = 0; m < 4; ++m)
#pragma unroll
                for (int n = 0; n < 4; ++n)
                    acc[m][n] = __builtin_amdgcn_mfma_f32_16x16x32_bf16(
                        af[m][kk], bfr[n][kk], acc[m][n], 0, 0, 0);
        __syncthreads();
    }

    const float* w1be = w1b + e*2*FFN_;
#pragma unroll
    for (int n = 0; n < 2; ++n) {
        int col = n0 + wn*32 + n*16 + (lane & 15);
        float bg = w1be[col];
        float bu = w1be[FFN_ + col];
#pragma unroll
        for (int m = 0; m < 4; ++m) {
            int rb2 = t0 + wm*64 + m*16 + (lane >> 4)*4;
#pragma unroll
            for (int i = 0; i < 4; ++i) {
                int t = rb2 + i;
                if (t < ce) {
                    float g = acc[m][n][i]   + bg;
                    float u = acc[m][n+2][i] + bu;
                    float hv = (g / (1.f + __expf(-g))) * u;
                    h[(size_t)(base + t)*FFN_ + col] = __float2bfloat16(hv);
                }
            }
        }
    }
}

__global__ __launch_bounds__(256) void gemm2_rs_kernel(
    const __hip_bfloat16* __restrict__ h, const float* __restrict__ w2,
    const float* __restrict__ w2b, const int* __restrict__ gtok,
    const float* __restrict__ gwt, const int* __restrict__ fill,
    float* __restrict__ out)
{
    const int e  = blockIdx.z;
    const int ce = fill[e];
    const int t0 = blockIdx.y * 128;
    if (t0 >= ce) return;
    const int n0   = blockIdx.x * 128;
    const int base = e * M_;
    const float* w2e = w2 + (size_t)e * HID_ * FFN_;

    __shared__ __align__(16) __hip_bfloat16 As[128*64];
    __shared__ __align__(16) __hip_bfloat16 Bs[128*64];

    const int tid  = threadIdx.x;
    const int lane = tid & 63;
    const int wid  = tid >> 6;
    const int wm   = wid >> 1;
    const int wn   = wid & 1;

    const __hip_bfloat16* asrc[4];
#pragma unroll
    for (int q = 0; q < 4; ++q) {
        int slot = q*256 + tid;
        int r = slot >> 3, p = slot & 7;
        int rr = min(t0 + r, ce - 1);
        int c = p ^ (r & 7);
        asrc[q] = h + (size_t)(base + rr) * FFN_ + c*8;
    }

    const int brow = tid >> 1;
    const int hk   = tid & 1;
    const float* bsrc = w2e + (size_t)(n0 + brow) * FFN_ + hk*32;

    f32x4 acc[4][4];
#pragma unroll
    for (int m = 0; m < 4; ++m)
#pragma unroll
        for (int n = 0; n < 4; ++n) acc[m][n] = (f32x4){0.f,0.f,0.f,0.f};

    float4 breg[8];
#pragma unroll
    for (int j = 0; j < 8; ++j) breg[j] = *(const float4*)(bsrc + j*4);

    for (int k0 = 0; k0 < FFN_; k0 += 64) {
#pragma unroll
        for (int q = 0; q < 4; ++q) {
            __builtin_amdgcn_global_load_lds(
                (GVOID*)(asrc[q] + k0),
                (LVOID*)(&As[(q*256 + wid*64)*8]), 16, 0, 0);
        }
#pragma unroll
        for (int cc = 0; cc < 4; ++cc) {
            union { bf16x8 v; short s8[8]; } u;
            const float* f0 = (const float*)&breg[2*cc];
#pragma unroll
            for (int j = 0; j < 8; ++j) u.s8[j] = f2bf(f0[j]);
            int c = hk*4 + cc, p = c ^ (brow & 7);
            *(bf16x8*)&Bs[brow*64 + p*8] = u.v;
        }
        __syncthreads();

        if (k0 + 64 < FFN_) {
#pragma unroll
            for (int j = 0; j < 8; ++j) breg[j] = *(const float4*)(bsrc + (k0+64) + j*4);
        }

        bf16x8 af[4][2], bfr[4][2];
#pragma unroll
        for (int m = 0; m < 4; ++m)
#pragma unroll
            for (int kk = 0; kk < 2; ++kk) {
                int r = wm*64 + m*16 + (lane & 15);
                int c = kk*4 + (lane >> 4), p = c ^ (r & 7);
                af[m][kk] = *(bf16x8*)&As[r*64 + p*8];
            }
#pragma unroll
        for (int n = 0; n < 4; ++n)
#pragma unroll
            for (int kk = 0; kk < 2; ++kk) {
                int r = wn*64 + n*16 + (lane & 15);
                int c = kk*4 + (lane >> 4), p = c ^ (r & 7);
                bfr[n][kk] = *(bf16x8*)&Bs[r*64 + p*8];
            }
#pragma unroll
        for (int kk = 0; kk < 2; ++kk)
#pragma unroll
            for (int m = 0; m < 4; ++m)
#pragma unroll
                for (int n = 0; n < 4; ++n)
                    acc[m][n] = __builtin_amdgcn_mfma_f32_16x16x32_bf16(
                        af[m][kk], bfr[n][kk], acc[m][n], 0, 0, 0);
        __syncthreads();
    }

    const float* w2be = w2b + e*HID_;
#pragma unroll
    for (int n = 0; n < 4; ++n) {
        int col = n0 + wn*64 + n*16 + (lane & 15);
        float bias = w2be[col];
#pragma unroll
        for (int m = 0; m < 4; ++m) {
            int rb2 = t0 + wm*64 + m*16 + (lane >> 4)*4;
#pragma unroll
            for (int i = 0; i < 4; ++i) {
                int t = rb2 + i;
                if (t < ce) {
                    int p   = base + t;
                    float w = gwt[p];
                    atomicAdd(&out[(size_t)gtok[p]*HID_ + col], w * (acc[m][n][i] + bias));
                }
            }
        }
    }
}

// ---------------------------------------------------------------------------
extern "C" void kernel_launch(void* const* d_in, const int* in_sizes, int n_in,
                              void* d_out, int out_size, void* d_ws, size_t ws_size,
                              hipStream_t stream)
{
    const float* x   = (const float*)d_in[0];
    const float* rw  = (const float*)d_in[1];
    const float* rb  = (const float*)d_in[2];
    const float* w1  = (const float*)d_in[3];
    const float* w1b = (const float*)d_in[4];
    const float* w2  = (const float*)d_in[5];
    const float* w2b = (const float*)d_in[6];

    float* out      = (float*)d_out;
    float* topk_out = out + (size_t)M_ * HID_;

    const size_t MB = 1024*1024;
    char*  ws   = (char*)d_ws;
    int*   fill = (int*)  (ws);                       // 8 ints (memset 32B)
    int*   pos  = (int*)  (ws + 128);                 // M*2 ints = 16 KB
    int*   gtok = (int*)  (ws + 65536);               // NP2 ints = 64 KB
    float* gwt  = (float*)(ws + 131072);              // NP2 floats = 64 KB
    __hip_bfloat16* xb    = (__hip_bfloat16*)(ws + 1*MB);    // 4 MB
    __hip_bfloat16* h     = (__hip_bfloat16*)(ws + 5*MB);    // 64 MB (NP2 x FFN)
    float*          dpair = (float*)         (ws + 69*MB);   // 128 MB (2 slices)
    __hip_bfloat16* w2bf  = (__hip_bfloat16*)(ws + 197*MB);  // 32 MB
    const bool tier2 = (ws_size >= 230*MB);

    hipMemsetAsync(fill, 0, E_ * sizeof(int), stream);

    router_kernel<<<M_, 64, 0, stream>>>(x, rw, rb, fill, gtok, gwt, pos,
                                         topk_out, xb);

    if (tier2) {
        dim3 g1(FFN_/64, M_/128, E_ + 1);    // (32, 16, 9): z=8 converts w2
        gemm1_kernel<<<g1, 256, 0, stream>>>(xb, w1, w1b, gtok, fill, h,
                                             w2, w2bf);

        dim3 g2(HID_/128, M_/128, 2*E_);     // (8, 16, 16) split-K=2
        gemm2_kernel<<<g2, 256, 0, stream>>>(h, w2bf, w2b, gwt, fill, dpair);

        combine_kernel<<<(M_*HID_)/(256*4), 256, 0, stream>>>(dpair, pos, out);
    } else {
        hipMemsetAsync(out, 0, (size_t)M_ * HID_ * sizeof(float), stream);

        dim3 g1(FFN_/64, M_/128, E_);
        gemm1_rs_kernel<<<g1, 256, 0, stream>>>(xb, w1, w1b, gtok, fill, h);

        dim3 g2(HID_/128, M_/128, E_);
        gemm2_rs_kernel<<<g2, 256, 0, stream>>>(h, w2, w2b, gtok, gwt, fill, out);
    }
}